// Round 10
// baseline (24.416 us; speedup 1.0000x reference)
//
#include <hip/hip_runtime.h>
#include <hip/hip_bf16.h>

// out[t,b,e] = sum_m (A[m,t,b,e] + i*B[m,t,b,e]) * w[b,t,m],  A=d_in[0], B=d_in[1]
// M=3, T=128, B=64, E=512.
// Output: bf16 flat interleaved pairs [T,B,E,2], slot order (B-mix, A-mix)
// -- verified passing rounds 5/6/8/9 (absmax 0.0625).
// Probe history: r6 MLP-double null; r8 nt-loads -14%; r9 nt-stores +1.6%.
// r10: 512-block blocked grid-stride (4 consecutive 8KB chunks per block per
// stream) to cut concurrent DRAM windows 12288 -> 3072 and lengthen row bursts.
#define MM 3
#define TT 128
#define BB 64
#define EE 512

typedef unsigned int u32x4 __attribute__((ext_vector_type(4)));

// round-to-nearest-even float32 -> bf16 (low 16 bits of result)
static __device__ __forceinline__ unsigned int f2bf(float x) {
    unsigned int u = __float_as_uint(x);
    return (u + 0x7FFFu + ((u >> 16) & 1u)) >> 16;
}

#define ITERS 4

__global__ __launch_bounds__(256) void qmix_kernel(
    const float* __restrict__ A, const float* __restrict__ Bv,
    const float* __restrict__ w, u32x4* __restrict__ out)
{
    const size_t TBE = (size_t)TT * BB * EE;                 // 4,194,304

    #pragma unroll
    for (int it = 0; it < ITERS; ++it) {
        // blocked partition: block b covers work items [b*1024, (b+1)*1024),
        // iteration `it` handles 256 consecutive items -> 8KB contiguous per
        // stream per iteration, 32KB contiguous per block per stream total.
        const int widx = blockIdx.x * (256 * ITERS) + it * 256 + threadIdx.x;
        const int e8   = widx & (EE / 8 - 1);                // 0..63
        const int tb   = widx >> 6;                          // t*B + b
        const int b    = tb & (BB - 1);
        const int t    = tb >> 6;

        // weights[b][t][m] — 96 KB, cache-resident, wave-uniform
        const int wbase = (b * TT + t) * MM;
        const float w0 = w[wbase + 0];
        const float w1 = w[wbase + 1];
        const float w2 = w[wbase + 2];

        const size_t base = (size_t)tb * EE + (size_t)e8 * 8;

        const float4 a0x = *(const float4*)(A  + base);
        const float4 a0y = *(const float4*)(A  + base + 4);
        const float4 a1x = *(const float4*)(A  + base + TBE);
        const float4 a1y = *(const float4*)(A  + base + TBE + 4);
        const float4 a2x = *(const float4*)(A  + base + 2 * TBE);
        const float4 a2y = *(const float4*)(A  + base + 2 * TBE + 4);
        const float4 b0x = *(const float4*)(Bv + base);
        const float4 b0y = *(const float4*)(Bv + base + 4);
        const float4 b1x = *(const float4*)(Bv + base + TBE);
        const float4 b1y = *(const float4*)(Bv + base + TBE + 4);
        const float4 b2x = *(const float4*)(Bv + base + 2 * TBE);
        const float4 b2y = *(const float4*)(Bv + base + 2 * TBE + 4);

        u32x4 pk0, pk1;
        {
            const float p0 = a0x.x * w0 + a1x.x * w1 + a2x.x * w2;
            const float q0 = b0x.x * w0 + b1x.x * w1 + b2x.x * w2;
            const float p1 = a0x.y * w0 + a1x.y * w1 + a2x.y * w2;
            const float q1 = b0x.y * w0 + b1x.y * w1 + b2x.y * w2;
            const float p2 = a0x.z * w0 + a1x.z * w1 + a2x.z * w2;
            const float q2 = b0x.z * w0 + b1x.z * w1 + b2x.z * w2;
            const float p3 = a0x.w * w0 + a1x.w * w1 + a2x.w * w2;
            const float q3 = b0x.w * w0 + b1x.w * w1 + b2x.w * w2;
            pk0.x = f2bf(q0) | (f2bf(p0) << 16);
            pk0.y = f2bf(q1) | (f2bf(p1) << 16);
            pk0.z = f2bf(q2) | (f2bf(p2) << 16);
            pk0.w = f2bf(q3) | (f2bf(p3) << 16);
        }
        {
            const float p4 = a0y.x * w0 + a1y.x * w1 + a2y.x * w2;
            const float q4 = b0y.x * w0 + b1y.x * w1 + b2y.x * w2;
            const float p5 = a0y.y * w0 + a1y.y * w1 + a2y.y * w2;
            const float q5 = b0y.y * w0 + b1y.y * w1 + b2y.y * w2;
            const float p6 = a0y.z * w0 + a1y.z * w1 + a2y.z * w2;
            const float q6 = b0y.z * w0 + b1y.z * w1 + b2y.z * w2;
            const float p7 = a0y.w * w0 + a1y.w * w1 + a2y.w * w2;
            const float q7 = b0y.w * w0 + b1y.w * w1 + b2y.w * w2;
            pk1.x = f2bf(q4) | (f2bf(p4) << 16);
            pk1.y = f2bf(q5) | (f2bf(p5) << 16);
            pk1.z = f2bf(q6) | (f2bf(p6) << 16);
            pk1.w = f2bf(q7) | (f2bf(p7) << 16);
        }

        const size_t q = base >> 2;
        __builtin_nontemporal_store(pk0, out + q);
        __builtin_nontemporal_store(pk1, out + q + 1);
    }
}

extern "C" void kernel_launch(void* const* d_in, const int* in_sizes, int n_in,
                              void* d_out, int out_size, void* d_ws, size_t ws_size,
                              hipStream_t stream) {
    const float* A  = (const float*)d_in[0];
    const float* Bv = (const float*)d_in[1];
    const float* w  = (const float*)d_in[2];   // weights [B,T,M]
    u32x4* out = (u32x4*)d_out;

    // total work items = T*B*E/8 = 524,288; 512 blocks x 256 thr x 4 iters
    const int block = 256;
    const int grid  = (TT * BB * EE / 8) / (block * ITERS);  // 512
    qmix_kernel<<<grid, block, 0, stream>>>(A, Bv, w, out);
}

// Round 11
// 23.504 us; speedup vs baseline: 1.0388x; 1.0388x over previous
//
#include <hip/hip_runtime.h>
#include <hip/hip_bf16.h>

// out[t,b,e] = sum_m (A[m,t,b,e] + i*B[m,t,b,e]) * w[b,t,m],  A=d_in[0], B=d_in[1]
// M=3, T=128, B=64, E=512.
// Output: bf16 flat interleaved pairs [T,B,E,2], slot order (B-mix, A-mix)
// -- verified passing rounds 5/6/8/9/10 (absmax 0.0625).
// Probe ledger: r6 MLP-double null; r8 nt-loads -14%; r9 nt-stores +1.6% (BEST
// 23.74us, 4.95 TB/s); r10 blocked-grid -3%. This is the r9 best config,
// reverted. 7-stream kernel above the 4.89 TB/s best-real-kernel reference
// (m146 RMSNorm); remaining gap to 6.29 TB/s 2-stream copy ceiling is
// structural (6 read streams + 1 write stream mixed).
#define MM 3
#define TT 128
#define BB 64
#define EE 512

typedef unsigned int u32x4 __attribute__((ext_vector_type(4)));

// round-to-nearest-even float32 -> bf16 (low 16 bits of result)
static __device__ __forceinline__ unsigned int f2bf(float x) {
    unsigned int u = __float_as_uint(x);
    return (u + 0x7FFFu + ((u >> 16) & 1u)) >> 16;
}

__global__ __launch_bounds__(256) void qmix_kernel(
    const float* __restrict__ A, const float* __restrict__ Bv,
    const float* __restrict__ w, u32x4* __restrict__ out)
{
    // Each thread: 8 consecutive e values (12 float4 loads, 2 16B nt stores).
    const int idx = blockIdx.x * blockDim.x + threadIdx.x;   // 0 .. T*B*E/8-1
    const int e8  = idx & (EE / 8 - 1);                      // 0..63
    const int tb  = idx >> 6;                                // t*B + b
    const int b   = tb & (BB - 1);
    const int t   = tb >> 6;

    // weights[b][t][m] — 96 KB, cache-resident, wave-uniform
    const int wbase = (b * TT + t) * MM;
    const float w0 = w[wbase + 0];
    const float w1 = w[wbase + 1];
    const float w2 = w[wbase + 2];

    const size_t TBE  = (size_t)TT * BB * EE;                // 4,194,304
    const size_t base = (size_t)tb * EE + (size_t)e8 * 8;    // element index

    // 12 independent cached loads (r8: nt loads regress badly)
    const float4 a0x = *(const float4*)(A  + base);
    const float4 a0y = *(const float4*)(A  + base + 4);
    const float4 a1x = *(const float4*)(A  + base + TBE);
    const float4 a1y = *(const float4*)(A  + base + TBE + 4);
    const float4 a2x = *(const float4*)(A  + base + 2 * TBE);
    const float4 a2y = *(const float4*)(A  + base + 2 * TBE + 4);
    const float4 b0x = *(const float4*)(Bv + base);
    const float4 b0y = *(const float4*)(Bv + base + 4);
    const float4 b1x = *(const float4*)(Bv + base + TBE);
    const float4 b1y = *(const float4*)(Bv + base + TBE + 4);
    const float4 b2x = *(const float4*)(Bv + base + 2 * TBE);
    const float4 b2y = *(const float4*)(Bv + base + 2 * TBE + 4);

    u32x4 pk0, pk1;
    {
        const float p0 = a0x.x * w0 + a1x.x * w1 + a2x.x * w2;
        const float q0 = b0x.x * w0 + b1x.x * w1 + b2x.x * w2;
        const float p1 = a0x.y * w0 + a1x.y * w1 + a2x.y * w2;
        const float q1 = b0x.y * w0 + b1x.y * w1 + b2x.y * w2;
        const float p2 = a0x.z * w0 + a1x.z * w1 + a2x.z * w2;
        const float q2 = b0x.z * w0 + b1x.z * w1 + b2x.z * w2;
        const float p3 = a0x.w * w0 + a1x.w * w1 + a2x.w * w2;
        const float q3 = b0x.w * w0 + b1x.w * w1 + b2x.w * w2;
        pk0.x = f2bf(q0) | (f2bf(p0) << 16);
        pk0.y = f2bf(q1) | (f2bf(p1) << 16);
        pk0.z = f2bf(q2) | (f2bf(p2) << 16);
        pk0.w = f2bf(q3) | (f2bf(p3) << 16);
    }
    {
        const float p4 = a0y.x * w0 + a1y.x * w1 + a2y.x * w2;
        const float q4 = b0y.x * w0 + b1y.x * w1 + b2y.x * w2;
        const float p5 = a0y.y * w0 + a1y.y * w1 + a2y.y * w2;
        const float q5 = b0y.y * w0 + b1y.y * w1 + b2y.y * w2;
        const float p6 = a0y.z * w0 + a1y.z * w1 + a2y.z * w2;
        const float q6 = b0y.z * w0 + b1y.z * w1 + b2y.z * w2;
        const float p7 = a0y.w * w0 + a1y.w * w1 + a2y.w * w2;
        const float q7 = b0y.w * w0 + b1y.w * w1 + b2y.w * w2;
        pk1.x = f2bf(q4) | (f2bf(p4) << 16);
        pk1.y = f2bf(q5) | (f2bf(p5) << 16);
        pk1.z = f2bf(q6) | (f2bf(p6) << 16);
        pk1.w = f2bf(q7) | (f2bf(p7) << 16);
    }

    // two consecutive 16B NON-TEMPORAL stores (zero-reuse output; r9 +1.6%)
    const size_t q = base >> 2;
    __builtin_nontemporal_store(pk0, out + q);
    __builtin_nontemporal_store(pk1, out + q + 1);
}

extern "C" void kernel_launch(void* const* d_in, const int* in_sizes, int n_in,
                              void* d_out, int out_size, void* d_ws, size_t ws_size,
                              hipStream_t stream) {
    const float* A  = (const float*)d_in[0];
    const float* Bv = (const float*)d_in[1];
    const float* w  = (const float*)d_in[2];   // weights [B,T,M]
    u32x4* out = (u32x4*)d_out;

    const int total_threads = TT * BB * EE / 8;  // 524,288
    const int block = 256;
    const int grid  = total_threads / block;     // 2048
    qmix_kernel<<<grid, block, 0, stream>>>(A, Bv, w, out);
}